// Round 2
// baseline (271.005 us; speedup 1.0000x reference)
//
#include <hip/hip_runtime.h>
#include <hip/hip_bf16.h>

#define NB 4
#define NC 512
#define NN 4096
#define NM 640
#define LOG2E 1.4426950408889634f

typedef __attribute__((ext_vector_type(8))) short bf16x8;
typedef __attribute__((ext_vector_type(4))) float f32x4;

__device__ __forceinline__ f32x4 mfma16(bf16x8 a, bf16x8 b, f32x4 c) {
  return __builtin_amdgcn_mfma_f32_16x16x32_bf16(a, b, c, 0, 0, 0);
}

__device__ __forceinline__ unsigned short f2bf(float f) {
  unsigned int u = __float_as_uint(f);
  u += 0x7fffu + ((u >> 16) & 1u);   // round-to-nearest-even
  return (unsigned short)(u >> 16);
}

// ---------------- pack weights: W[640][512] bf16 + bias[640] f32 ----------------
__global__ void pack_w(const float* __restrict__ wq, const float* __restrict__ bq,
                       const float* __restrict__ wk, const float* __restrict__ bk,
                       const float* __restrict__ wv, const float* __restrict__ bv,
                       unsigned short* __restrict__ W, float* __restrict__ bias) {
  int idx = blockIdx.x * 256 + threadIdx.x;
  if (idx < NM * NC) {
    int r = idx >> 9, c = idx & (NC - 1);
    float v;
    if (r < 64) v = wq[r * NC + c];
    else if (r < 128) v = wk[(r - 64) * NC + c];
    else v = wv[(r - 128) * NC + c];
    W[idx] = f2bf(v);
  }
  if (idx < NM)
    bias[idx] = (idx < 64) ? bq[idx] : (idx < 128 ? bk[idx - 64] : bv[idx - 128]);
}

// ---------------- transpose + convert: x[b][c][n] f32 -> XT[b][n][c] bf16 ----------------
__global__ void xpose(const float* __restrict__ x, unsigned short* __restrict__ XT) {
  __shared__ float t[64][65];
  int b = blockIdx.z;
  int c0 = blockIdx.y * 64, n0 = blockIdx.x * 64;
  int tx = threadIdx.x & 63, ty = threadIdx.x >> 6;  // 256 threads
  const float* xb = x + (size_t)b * NC * NN;
#pragma unroll
  for (int i = 0; i < 16; ++i) {
    int c = i * 4 + ty;
    t[c][tx] = xb[(size_t)(c0 + c) * NN + n0 + tx];
  }
  __syncthreads();
  unsigned short* xtb = XT + (size_t)b * NN * NC;
#pragma unroll
  for (int i = 0; i < 16; ++i) {
    int n = i * 4 + ty;
    xtb[(size_t)(n0 + n) * NC + c0 + tx] = f2bf(t[tx][n]);
  }
}

// ---------------- QKV projection GEMM (NT): C[m][n] = sum_k W[m][k]*XT[n][k] ----------------
// grid (8, 10, 4), 512 threads. Tile: 64 m x 512 n (8 waves x 64 n each).
__global__ __launch_bounds__(512) void gemm_qkv(
    const unsigned short* __restrict__ W, const float* __restrict__ bias,
    const unsigned short* __restrict__ XT,
    unsigned short* __restrict__ QT, unsigned short* __restrict__ KT,
    unsigned short* __restrict__ V) {
  int b = blockIdx.z;
  int m0 = blockIdx.y * 64;
  int wave = threadIdx.x >> 6, lane = threadIdx.x & 63;
  int nw = blockIdx.x * 512 + wave * 64;
  int lcol = lane & 15, lkg = lane >> 4;
  const unsigned short* xtb = XT + (size_t)b * NN * NC;
  f32x4 acc[4][4] = {};
  for (int k0 = 0; k0 < NC; k0 += 32) {
    int ko = k0 + lkg * 8;
    bf16x8 afr[4], bfr[4];
#pragma unroll
    for (int i = 0; i < 4; ++i)
      afr[i] = *reinterpret_cast<const bf16x8*>(W + (size_t)(m0 + 16 * i + lcol) * NC + ko);
#pragma unroll
    for (int j = 0; j < 4; ++j)
      bfr[j] = *reinterpret_cast<const bf16x8*>(xtb + (size_t)(nw + 16 * j + lcol) * NC + ko);
#pragma unroll
    for (int i = 0; i < 4; ++i)
#pragma unroll
      for (int j = 0; j < 4; ++j)
        acc[i][j] = mfma16(afr[i], bfr[j], acc[i][j]);
  }
  int rbase = lkg * 4;  // D row = (lane>>4)*4 + r, col = lane&15
  if (m0 < 128) {
    // q or k rows -> write transposed [n][64] bf16
    unsigned short* T = (m0 < 64) ? (QT + (size_t)b * NN * 64) : (KT + (size_t)b * NN * 64);
    int mb = m0 & 63;
#pragma unroll
    for (int j = 0; j < 4; ++j) {
      int n = nw + 16 * j + lcol;
#pragma unroll
      for (int i = 0; i < 4; ++i) {
        int m = mb + 16 * i + rbase;
        union { unsigned short h[4]; unsigned long long u; } pk;
#pragma unroll
        for (int r = 0; r < 4; ++r)
          pk.h[r] = f2bf(acc[i][j][r] + bias[m0 + 16 * i + rbase + r]);
        *reinterpret_cast<unsigned long long*>(T + (size_t)n * 64 + m) = pk.u;
      }
    }
  } else {
    // v rows -> row-major [c][n] bf16
    unsigned short* vb = V + (size_t)b * NC * NN;
#pragma unroll
    for (int i = 0; i < 4; ++i) {
#pragma unroll
      for (int r = 0; r < 4; ++r) {
        int m = m0 + 16 * i + rbase + r;
        float bs = bias[m];
        int c = m - 128;
#pragma unroll
        for (int j = 0; j < 4; ++j) {
          int n = nw + 16 * j + lcol;
          vb[(size_t)c * NN + n] = f2bf(acc[i][j][r] + bs);
        }
      }
    }
  }
}

// ---------------- fused attention ----------------
// grid 256 = 4 batches x 64 column-blocks (JB=64). 512 threads (8 waves).
// Wave w owns output rows c in [64w, 64w+64), all 64 columns. Online softmax over i.
__global__ __launch_bounds__(512) void attn_fwd(
    const unsigned short* __restrict__ QT, const unsigned short* __restrict__ KT,
    const unsigned short* __restrict__ V, const float* __restrict__ x,
    const float* __restrict__ gamma, float* __restrict__ out) {
  int b = blockIdx.x >> 6;
  int j0 = (blockIdx.x & 63) * 64;
  int wave = threadIdx.x >> 6, lane = threadIdx.x & 63;
  int lcol = lane & 15, lkg = lane >> 4;

  __shared__ float colmax[64][9];                       // [j][wave] (+pad); reused as lsum at end
  __shared__ __align__(16) unsigned short plds[64 * 128];  // P^T [j][i], XOR-swizzled

  const unsigned short* qt = QT + (size_t)b * NN * 64;
  const unsigned short* kt = KT + (size_t)b * NN * 64;
  const unsigned short* vp = V + (size_t)b * NC * NN;

  // K fragments for this j-block: resident in registers for the whole loop
  bf16x8 kfr[4][2];
#pragma unroll
  for (int fn = 0; fn < 4; ++fn)
#pragma unroll
    for (int ks = 0; ks < 2; ++ks)
      kfr[fn][ks] = *reinterpret_cast<const bf16x8*>(
          kt + (size_t)(j0 + 16 * fn + lcol) * 64 + ks * 32 + lkg * 8);

  f32x4 oacc[4][4] = {};  // [cm][fn]
  float m_r[4], l_r[4];
#pragma unroll
  for (int fn = 0; fn < 4; ++fn) { m_r[fn] = -1e30f; l_r[fn] = 0.f; }

  for (int i0 = 0; i0 < NN; i0 += 128) {
    // ---- S strip: rows [i0+16*wave, +16) x 64 cols ----
    f32x4 s[4] = {};
    bf16x8 qfr[2];
#pragma unroll
    for (int ks = 0; ks < 2; ++ks)
      qfr[ks] = *reinterpret_cast<const bf16x8*>(
          qt + (size_t)(i0 + 16 * wave + lcol) * 64 + ks * 32 + lkg * 8);
#pragma unroll
    for (int ks = 0; ks < 2; ++ks)
#pragma unroll
      for (int fn = 0; fn < 4; ++fn)
        s[fn] = mfma16(qfr[ks], kfr[fn][ks], s[fn]);

    // per-column max over the 16 strip rows
#pragma unroll
    for (int fn = 0; fn < 4; ++fn) {
      float v = fmaxf(fmaxf(s[fn][0], s[fn][1]), fmaxf(s[fn][2], s[fn][3]));
      v = fmaxf(v, __shfl_xor(v, 16));
      v = fmaxf(v, __shfl_xor(v, 32));
      if (lane < 16) colmax[16 * fn + lane][wave] = v;
    }
    __syncthreads();

    // ---- softmax update (per lane: its 4 columns j = 16fn+lcol) ----
    float r_f[4];
#pragma unroll
    for (int fn = 0; fn < 4; ++fn) {
      const float* cmr = colmax[16 * fn + lcol];
      float nm = m_r[fn];
#pragma unroll
      for (int w = 0; w < 8; ++w) nm = fmaxf(nm, cmr[w]);
      r_f[fn] = exp2f((m_r[fn] - nm) * LOG2E);
      float p[4];
#pragma unroll
      for (int r = 0; r < 4; ++r) p[r] = exp2f((s[fn][r] - nm) * LOG2E);
      float cs = p[0] + p[1] + p[2] + p[3];
      cs += __shfl_xor(cs, 16);
      cs += __shfl_xor(cs, 32);
      l_r[fn] = l_r[fn] * r_f[fn] + cs;   // NOTE: per-wave partial; reduced across waves after loop
      m_r[fn] = nm;
      // write P^T[j][i] bf16, swizzled: i_local = 16*wave + lkg*4 + r
      union { unsigned short h[4]; unsigned long long u; } pk;
#pragma unroll
      for (int r = 0; r < 4; ++r) pk.h[r] = f2bf(p[r]);
      int j = 16 * fn + lcol;
      int byteoff = (j * 256 + wave * 32 + lkg * 8) ^ ((j & 7) << 4);
      *reinterpret_cast<unsigned long long*>(reinterpret_cast<char*>(plds) + byteoff) = pk.u;
    }
    // rescale accumulator
#pragma unroll
    for (int cm = 0; cm < 4; ++cm)
#pragma unroll
      for (int fn = 0; fn < 4; ++fn)
#pragma unroll
        for (int r = 0; r < 4; ++r) oacc[cm][fn][r] *= r_f[fn];
    __syncthreads();

    // ---- PV: O[64c][64j] += V[c][i-block] * P^T ----
#pragma unroll
    for (int ks = 0; ks < 4; ++ks) {
      bf16x8 pfr[4];
#pragma unroll
      for (int fn = 0; fn < 4; ++fn) {
        int j = 16 * fn + lcol;
        int byteoff = (j * 256 + ks * 64 + lkg * 16) ^ ((j & 7) << 4);
        pfr[fn] = *reinterpret_cast<const bf16x8*>(reinterpret_cast<char*>(plds) + byteoff);
      }
#pragma unroll
      for (int cm = 0; cm < 4; ++cm) {
        bf16x8 vfr = *reinterpret_cast<const bf16x8*>(
            vp + (size_t)(64 * wave + 16 * cm + lcol) * NN + i0 + ks * 32 + lkg * 8);
#pragma unroll
        for (int fn = 0; fn < 4; ++fn)
          oacc[cm][fn] = mfma16(vfr, pfr[fn], oacc[cm][fn]);
      }
    }
  }

  // ---- cross-wave l reduction: l_r held only this wave's strips' partial sums ----
  // (reuse colmax LDS; all loop-time reads of it are complete)
#pragma unroll
  for (int fn = 0; fn < 4; ++fn)
    if (lkg == 0) colmax[16 * fn + lcol][wave] = l_r[fn];
  __syncthreads();
#pragma unroll
  for (int fn = 0; fn < 4; ++fn) {
    const float* lr = colmax[16 * fn + lcol];
    float lt = 0.f;
#pragma unroll
    for (int w = 0; w < 8; ++w) lt += lr[w];
    l_r[fn] = lt;
  }

  // ---- epilogue: out = gamma * O/l + x ----
  float g = gamma[0];
  const float* xb = x + (size_t)b * NC * NN;
  float* ob = out + (size_t)b * NC * NN;
#pragma unroll
  for (int fn = 0; fn < 4; ++fn) {
    float sc = g / l_r[fn];
    int j = j0 + 16 * fn + lcol;
#pragma unroll
    for (int cm = 0; cm < 4; ++cm) {
      int c = 64 * wave + 16 * cm + lkg * 4;
#pragma unroll
      for (int r = 0; r < 4; ++r) {
        size_t idx = (size_t)(c + r) * NN + j;
        ob[idx] = oacc[cm][fn][r] * sc + xb[idx];
      }
    }
  }
}

extern "C" void kernel_launch(void* const* d_in, const int* in_sizes, int n_in,
                              void* d_out, int out_size, void* d_ws, size_t ws_size,
                              hipStream_t stream) {
  const float* x  = (const float*)d_in[0];
  const float* wq = (const float*)d_in[1];
  const float* bq = (const float*)d_in[2];
  const float* wk = (const float*)d_in[3];
  const float* bk = (const float*)d_in[4];
  const float* wv = (const float*)d_in[5];
  const float* bv = (const float*)d_in[6];
  const float* gm = (const float*)d_in[7];
  float* out = (float*)d_out;

  char* ws = (char*)d_ws;
  unsigned short* XT = (unsigned short*)(ws);                        // 16 MB
  unsigned short* Vb = (unsigned short*)(ws + (size_t)16 * 1024 * 1024);  // 16 MB
  unsigned short* QT = (unsigned short*)(ws + (size_t)32 * 1024 * 1024);  // 2 MB
  unsigned short* KT = (unsigned short*)(ws + (size_t)34 * 1024 * 1024);  // 2 MB
  unsigned short* Wp = (unsigned short*)(ws + (size_t)36 * 1024 * 1024);  // 640 KB
  float* biasp       = (float*)(ws + (size_t)36 * 1024 * 1024 + 700 * 1024);

  pack_w<<<(NM * NC + 255) / 256, 256, 0, stream>>>(wq, bq, wk, bk, wv, bv, Wp, biasp);
  xpose<<<dim3(NN / 64, NC / 64, NB), 256, 0, stream>>>(x, XT);
  gemm_qkv<<<dim3(NN / 512, NM / 64, NB), 512, 0, stream>>>(Wp, biasp, XT, QT, KT, Vb);
  attn_fwd<<<256, 512, 0, stream>>>(QT, KT, Vb, x, gm, out);
}

// Round 3
// 264.944 us; speedup vs baseline: 1.0229x; 1.0229x over previous
//
#include <hip/hip_runtime.h>
#include <hip/hip_bf16.h>

#define NB 4
#define NC 512
#define NN 4096
#define NM 640
#define LOG2E 1.4426950408889634f

typedef __attribute__((ext_vector_type(8))) short bf16x8;
typedef __attribute__((ext_vector_type(4))) float f32x4;

__device__ __forceinline__ f32x4 mfma16(bf16x8 a, bf16x8 b, f32x4 c) {
  return __builtin_amdgcn_mfma_f32_16x16x32_bf16(a, b, c, 0, 0, 0);
}

__device__ __forceinline__ unsigned short f2bf(float f) {
  unsigned int u = __float_as_uint(f);
  u += 0x7fffu + ((u >> 16) & 1u);   // round-to-nearest-even
  return (unsigned short)(u >> 16);
}

// ---------------- pack weights: W[640][512] bf16 + bias[640] f32 ----------------
__global__ void pack_w(const float* __restrict__ wq, const float* __restrict__ bq,
                       const float* __restrict__ wk, const float* __restrict__ bk,
                       const float* __restrict__ wv, const float* __restrict__ bv,
                       unsigned short* __restrict__ W, float* __restrict__ bias) {
  int idx = blockIdx.x * 256 + threadIdx.x;
  if (idx < NM * NC) {
    int r = idx >> 9, c = idx & (NC - 1);
    float v;
    if (r < 64) v = wq[r * NC + c];
    else if (r < 128) v = wk[(r - 64) * NC + c];
    else v = wv[(r - 128) * NC + c];
    W[idx] = f2bf(v);
  }
  if (idx < NM)
    bias[idx] = (idx < 64) ? bq[idx] : (idx < 128 ? bk[idx - 64] : bv[idx - 128]);
}

// ---------------- transpose + convert: x[b][c][n] f32 -> XT[b][n][c] bf16 ----------------
__global__ void xpose(const float* __restrict__ x, unsigned short* __restrict__ XT) {
  __shared__ float t[64][65];
  int b = blockIdx.z;
  int c0 = blockIdx.y * 64, n0 = blockIdx.x * 64;
  int tx = threadIdx.x & 63, ty = threadIdx.x >> 6;  // 256 threads
  const float* xb = x + (size_t)b * NC * NN;
#pragma unroll
  for (int i = 0; i < 16; ++i) {
    int c = i * 4 + ty;
    t[c][tx] = xb[(size_t)(c0 + c) * NN + n0 + tx];
  }
  __syncthreads();
  unsigned short* xtb = XT + (size_t)b * NN * NC;
#pragma unroll
  for (int i = 0; i < 16; ++i) {
    int n = i * 4 + ty;
    xtb[(size_t)(n0 + n) * NC + c0 + tx] = f2bf(t[tx][n]);
  }
}

// ---------------- QKV projection GEMM (NT): C[m][n] = sum_k W[m][k]*XT[n][k] ----------------
__global__ __launch_bounds__(512) void gemm_qkv(
    const unsigned short* __restrict__ W, const float* __restrict__ bias,
    const unsigned short* __restrict__ XT,
    unsigned short* __restrict__ QT, unsigned short* __restrict__ KT,
    unsigned short* __restrict__ V) {
  int b = blockIdx.z;
  int m0 = blockIdx.y * 64;
  int wave = threadIdx.x >> 6, lane = threadIdx.x & 63;
  int nw = blockIdx.x * 512 + wave * 64;
  int lcol = lane & 15, lkg = lane >> 4;
  const unsigned short* xtb = XT + (size_t)b * NN * NC;
  f32x4 acc[4][4] = {};
  for (int k0 = 0; k0 < NC; k0 += 32) {
    int ko = k0 + lkg * 8;
    bf16x8 afr[4], bfr[4];
#pragma unroll
    for (int i = 0; i < 4; ++i)
      afr[i] = *reinterpret_cast<const bf16x8*>(W + (size_t)(m0 + 16 * i + lcol) * NC + ko);
#pragma unroll
    for (int j = 0; j < 4; ++j)
      bfr[j] = *reinterpret_cast<const bf16x8*>(xtb + (size_t)(nw + 16 * j + lcol) * NC + ko);
#pragma unroll
    for (int i = 0; i < 4; ++i)
#pragma unroll
      for (int j = 0; j < 4; ++j)
        acc[i][j] = mfma16(afr[i], bfr[j], acc[i][j]);
  }
  int rbase = lkg * 4;  // D row = (lane>>4)*4 + r, col = lane&15
  if (m0 < 128) {
    unsigned short* T = (m0 < 64) ? (QT + (size_t)b * NN * 64) : (KT + (size_t)b * NN * 64);
    int mb = m0 & 63;
#pragma unroll
    for (int j = 0; j < 4; ++j) {
      int n = nw + 16 * j + lcol;
#pragma unroll
      for (int i = 0; i < 4; ++i) {
        int m = mb + 16 * i + rbase;
        union { unsigned short h[4]; unsigned long long u; } pk;
#pragma unroll
        for (int r = 0; r < 4; ++r)
          pk.h[r] = f2bf(acc[i][j][r] + bias[m0 + 16 * i + rbase + r]);
        *reinterpret_cast<unsigned long long*>(T + (size_t)n * 64 + m) = pk.u;
      }
    }
  } else {
    unsigned short* vb = V + (size_t)b * NC * NN;
#pragma unroll
    for (int i = 0; i < 4; ++i) {
#pragma unroll
      for (int r = 0; r < 4; ++r) {
        int m = m0 + 16 * i + rbase + r;
        float bs = bias[m];
        int c = m - 128;
#pragma unroll
        for (int j = 0; j < 4; ++j) {
          int n = nw + 16 * j + lcol;
          vb[(size_t)c * NN + n] = f2bf(acc[i][j][r] + bs);
        }
      }
    }
  }
}

// ---------------- fused attention ----------------
// grid 256; block b,jb chosen so batch b occupies XCD pair {2b,2b+1} (blockIdx%8 -> XCD).
// 512 threads (8 waves). Wave w owns output rows c in [64w, 64w+64). Online softmax over i.
__global__ __launch_bounds__(512) void attn_fwd(
    const unsigned short* __restrict__ QT, const unsigned short* __restrict__ KT,
    const unsigned short* __restrict__ V, const float* __restrict__ x,
    const float* __restrict__ gamma, float* __restrict__ out) {
  int bid = blockIdx.x;
  int b = (bid & 7) >> 1;                       // XCD pair {2b,2b+1}
  int jb = ((bid >> 3) << 1) | (bid & 1);       // 0..63, bijective with (b,jb)
  int j0 = jb * 64;
  int wave = threadIdx.x >> 6, lane = threadIdx.x & 63;
  int lcol = lane & 15, lkg = lane >> 4;

  __shared__ float colmax[64][9];                          // [j][wave] (+pad); reused for l-reduce
  __shared__ __align__(16) unsigned short plds[64 * 128];  // P^T [j][i], XOR-swizzled

  const unsigned short* qt = QT + (size_t)b * NN * 64;
  const unsigned short* kt = KT + (size_t)b * NN * 64;
  const unsigned short* vp = V + (size_t)b * NC * NN;

  // K fragments for this j-block: resident in registers for the whole loop
  bf16x8 kfr[4][2];
#pragma unroll
  for (int fn = 0; fn < 4; ++fn)
#pragma unroll
    for (int ks = 0; ks < 2; ++ks)
      kfr[fn][ks] = *reinterpret_cast<const bf16x8*>(
          kt + (size_t)(j0 + 16 * fn + lcol) * 64 + ks * 32 + lkg * 8);

  f32x4 oacc[4][4] = {};  // [cm][fn]
  float m_r[4], l_r[4];
#pragma unroll
  for (int fn = 0; fn < 4; ++fn) { m_r[fn] = -1e30f; l_r[fn] = 0.f; }

  for (int i0 = 0; i0 < NN; i0 += 128) {
    // ---- issue Q loads FIRST (FIFO: waiting on Q keeps V in flight) ----
    bf16x8 qfr[2];
#pragma unroll
    for (int ks = 0; ks < 2; ++ks)
      qfr[ks] = *reinterpret_cast<const bf16x8*>(
          qt + (size_t)(i0 + 16 * wave + lcol) * 64 + ks * 32 + lkg * 8);

    // ---- prefetch ALL V fragments for this i-block into registers (64 VGPR) ----
    // consumed only in PV, after 2 barriers + softmax: latency fully hidden
    bf16x8 vfr[4][4];  // [ks][cm]
#pragma unroll
    for (int ks = 0; ks < 4; ++ks)
#pragma unroll
      for (int cm = 0; cm < 4; ++cm)
        vfr[ks][cm] = *reinterpret_cast<const bf16x8*>(
            vp + (size_t)(64 * wave + 16 * cm + lcol) * NN + i0 + ks * 32 + lkg * 8);

    // ---- S strip: rows [i0+16*wave, +16) x 64 cols ----
    f32x4 s[4] = {};
#pragma unroll
    for (int ks = 0; ks < 2; ++ks)
#pragma unroll
      for (int fn = 0; fn < 4; ++fn)
        s[fn] = mfma16(qfr[ks], kfr[fn][ks], s[fn]);

    // per-column max over the 16 strip rows
#pragma unroll
    for (int fn = 0; fn < 4; ++fn) {
      float v = fmaxf(fmaxf(s[fn][0], s[fn][1]), fmaxf(s[fn][2], s[fn][3]));
      v = fmaxf(v, __shfl_xor(v, 16));
      v = fmaxf(v, __shfl_xor(v, 32));
      if (lane < 16) colmax[16 * fn + lane][wave] = v;
    }
    __syncthreads();

    // ---- softmax update (per lane: its 4 columns j = 16fn+lcol) ----
#pragma unroll
    for (int fn = 0; fn < 4; ++fn) {
      const float* cmr = colmax[16 * fn + lcol];
      float nm = cmr[0];
#pragma unroll
      for (int w = 1; w < 8; ++w) nm = fmaxf(nm, cmr[w]);
      // defer-max (T13): only rescale when the max grew by more than THR=8.
      // decision is identical across waves (colmax shared + same history) -> l partials consistent.
      if (!__all(nm - m_r[fn] <= 8.0f)) {
        float rf = exp2f((m_r[fn] - nm) * LOG2E);
        l_r[fn] *= rf;
#pragma unroll
        for (int cm = 0; cm < 4; ++cm)
#pragma unroll
          for (int r = 0; r < 4; ++r) oacc[cm][fn][r] *= rf;
        m_r[fn] = nm;
      }
      float p[4];
#pragma unroll
      for (int r = 0; r < 4; ++r) p[r] = exp2f((s[fn][r] - m_r[fn]) * LOG2E);
      float cs = p[0] + p[1] + p[2] + p[3];
      cs += __shfl_xor(cs, 16);
      cs += __shfl_xor(cs, 32);
      l_r[fn] += cs;   // per-wave partial; reduced across waves after loop
      // write P^T[j][i] bf16, swizzled: i_local = 16*wave + lkg*4 + r
      union { unsigned short h[4]; unsigned long long u; } pk;
#pragma unroll
      for (int r = 0; r < 4; ++r) pk.h[r] = f2bf(p[r]);
      int j = 16 * fn + lcol;
      int byteoff = (j * 256 + wave * 32 + lkg * 8) ^ ((j & 7) << 4);
      *reinterpret_cast<unsigned long long*>(reinterpret_cast<char*>(plds) + byteoff) = pk.u;
    }
    __syncthreads();

    // ---- PV: O[64c][64j] += V[c][i-block] * P^T (V already in registers) ----
#pragma unroll
    for (int ks = 0; ks < 4; ++ks) {
      bf16x8 pfr[4];
#pragma unroll
      for (int fn = 0; fn < 4; ++fn) {
        int j = 16 * fn + lcol;
        int byteoff = (j * 256 + ks * 64 + lkg * 16) ^ ((j & 7) << 4);
        pfr[fn] = *reinterpret_cast<const bf16x8*>(reinterpret_cast<char*>(plds) + byteoff);
      }
#pragma unroll
      for (int cm = 0; cm < 4; ++cm)
#pragma unroll
        for (int fn = 0; fn < 4; ++fn)
          oacc[cm][fn] = mfma16(vfr[ks][cm], pfr[fn], oacc[cm][fn]);
    }
  }

  // ---- cross-wave l reduction (reuse colmax LDS) ----
#pragma unroll
  for (int fn = 0; fn < 4; ++fn)
    if (lkg == 0) colmax[16 * fn + lcol][wave] = l_r[fn];
  __syncthreads();
#pragma unroll
  for (int fn = 0; fn < 4; ++fn) {
    const float* lr = colmax[16 * fn + lcol];
    float lt = 0.f;
#pragma unroll
    for (int w = 0; w < 8; ++w) lt += lr[w];
    l_r[fn] = lt;
  }

  // ---- epilogue: out = gamma * O/l + x ----
  float g = gamma[0];
  const float* xb = x + (size_t)b * NC * NN;
  float* ob = out + (size_t)b * NC * NN;
#pragma unroll
  for (int fn = 0; fn < 4; ++fn) {
    float sc = g / l_r[fn];
    int j = j0 + 16 * fn + lcol;
#pragma unroll
    for (int cm = 0; cm < 4; ++cm) {
      int c = 64 * wave + 16 * cm + lkg * 4;
#pragma unroll
      for (int r = 0; r < 4; ++r) {
        size_t idx = (size_t)(c + r) * NN + j;
        ob[idx] = oacc[cm][fn][r] * sc + xb[idx];
      }
    }
  }
}

extern "C" void kernel_launch(void* const* d_in, const int* in_sizes, int n_in,
                              void* d_out, int out_size, void* d_ws, size_t ws_size,
                              hipStream_t stream) {
  const float* x  = (const float*)d_in[0];
  const float* wq = (const float*)d_in[1];
  const float* bq = (const float*)d_in[2];
  const float* wk = (const float*)d_in[3];
  const float* bk = (const float*)d_in[4];
  const float* wv = (const float*)d_in[5];
  const float* bv = (const float*)d_in[6];
  const float* gm = (const float*)d_in[7];
  float* out = (float*)d_out;

  char* ws = (char*)d_ws;
  unsigned short* XT = (unsigned short*)(ws);                        // 16 MB
  unsigned short* Vb = (unsigned short*)(ws + (size_t)16 * 1024 * 1024);  // 16 MB
  unsigned short* QT = (unsigned short*)(ws + (size_t)32 * 1024 * 1024);  // 2 MB
  unsigned short* KT = (unsigned short*)(ws + (size_t)34 * 1024 * 1024);  // 2 MB
  unsigned short* Wp = (unsigned short*)(ws + (size_t)36 * 1024 * 1024);  // 640 KB
  float* biasp       = (float*)(ws + (size_t)36 * 1024 * 1024 + 700 * 1024);

  pack_w<<<(NM * NC + 255) / 256, 256, 0, stream>>>(wq, bq, wk, bk, wv, bv, Wp, biasp);
  xpose<<<dim3(NN / 64, NC / 64, NB), 256, 0, stream>>>(x, XT);
  gemm_qkv<<<dim3(NN / 512, NM / 64, NB), 512, 0, stream>>>(Wp, biasp, XT, QT, KT, Vb);
  attn_fwd<<<256, 512, 0, stream>>>(QT, KT, Vb, x, gm, out);
}

// Round 4
// 258.939 us; speedup vs baseline: 1.0466x; 1.0232x over previous
//
#include <hip/hip_runtime.h>
#include <hip/hip_bf16.h>

#define NB 4
#define NC 512
#define NN 4096
#define NM 640
#define LOG2E 1.4426950408889634f

typedef __attribute__((ext_vector_type(8))) short bf16x8;
typedef __attribute__((ext_vector_type(4))) float f32x4;

__device__ __forceinline__ f32x4 mfma16(bf16x8 a, bf16x8 b, f32x4 c) {
  return __builtin_amdgcn_mfma_f32_16x16x32_bf16(a, b, c, 0, 0, 0);
}

__device__ __forceinline__ unsigned short f2bf(float f) {
  unsigned int u = __float_as_uint(f);
  u += 0x7fffu + ((u >> 16) & 1u);   // round-to-nearest-even
  return (unsigned short)(u >> 16);
}

// ---------------- pack weights: W[640][512] bf16 + bias[640] f32 ----------------
__global__ void pack_w(const float* __restrict__ wq, const float* __restrict__ bq,
                       const float* __restrict__ wk, const float* __restrict__ bk,
                       const float* __restrict__ wv, const float* __restrict__ bv,
                       unsigned short* __restrict__ W, float* __restrict__ bias) {
  int idx = blockIdx.x * 256 + threadIdx.x;
  if (idx < NM * NC) {
    int r = idx >> 9, c = idx & (NC - 1);
    float v;
    if (r < 64) v = wq[r * NC + c];
    else if (r < 128) v = wk[(r - 64) * NC + c];
    else v = wv[(r - 128) * NC + c];
    W[idx] = f2bf(v);
  }
  if (idx < NM)
    bias[idx] = (idx < 64) ? bq[idx] : (idx < 128 ? bk[idx - 64] : bv[idx - 128]);
}

// ---------------- transpose + convert: x[b][c][n] f32 -> XT[b][n][c] bf16 ----------------
__global__ void xpose(const float* __restrict__ x, unsigned short* __restrict__ XT) {
  __shared__ float t[64][65];
  int b = blockIdx.z;
  int c0 = blockIdx.y * 64, n0 = blockIdx.x * 64;
  int tx = threadIdx.x & 63, ty = threadIdx.x >> 6;  // 256 threads
  const float* xb = x + (size_t)b * NC * NN;
#pragma unroll
  for (int i = 0; i < 16; ++i) {
    int c = i * 4 + ty;
    t[c][tx] = xb[(size_t)(c0 + c) * NN + n0 + tx];
  }
  __syncthreads();
  unsigned short* xtb = XT + (size_t)b * NN * NC;
#pragma unroll
  for (int i = 0; i < 16; ++i) {
    int n = i * 4 + ty;
    xtb[(size_t)(n0 + n) * NC + c0 + tx] = f2bf(t[tx][n]);
  }
}

// ---------------- QKV projection GEMM (NT): C[m][n] = sum_k W[m][k]*XT[n][k] ----------------
__global__ __launch_bounds__(512) void gemm_qkv(
    const unsigned short* __restrict__ W, const float* __restrict__ bias,
    const unsigned short* __restrict__ XT,
    unsigned short* __restrict__ QT, unsigned short* __restrict__ KT,
    unsigned short* __restrict__ V) {
  int b = blockIdx.z;
  int m0 = blockIdx.y * 64;
  int wave = threadIdx.x >> 6, lane = threadIdx.x & 63;
  int nw = blockIdx.x * 512 + wave * 64;
  int lcol = lane & 15, lkg = lane >> 4;
  const unsigned short* xtb = XT + (size_t)b * NN * NC;
  f32x4 acc[4][4] = {};
  for (int k0 = 0; k0 < NC; k0 += 32) {
    int ko = k0 + lkg * 8;
    bf16x8 afr[4], bfr[4];
#pragma unroll
    for (int i = 0; i < 4; ++i)
      afr[i] = *reinterpret_cast<const bf16x8*>(W + (size_t)(m0 + 16 * i + lcol) * NC + ko);
#pragma unroll
    for (int j = 0; j < 4; ++j)
      bfr[j] = *reinterpret_cast<const bf16x8*>(xtb + (size_t)(nw + 16 * j + lcol) * NC + ko);
#pragma unroll
    for (int i = 0; i < 4; ++i)
#pragma unroll
      for (int j = 0; j < 4; ++j)
        acc[i][j] = mfma16(afr[i], bfr[j], acc[i][j]);
  }
  int rbase = lkg * 4;  // D row = (lane>>4)*4 + r, col = lane&15
  if (m0 < 128) {
    unsigned short* T = (m0 < 64) ? (QT + (size_t)b * NN * 64) : (KT + (size_t)b * NN * 64);
    int mb = m0 & 63;
#pragma unroll
    for (int j = 0; j < 4; ++j) {
      int n = nw + 16 * j + lcol;
#pragma unroll
      for (int i = 0; i < 4; ++i) {
        int m = mb + 16 * i + rbase;
        union { unsigned short h[4]; unsigned long long u; } pk;
#pragma unroll
        for (int r = 0; r < 4; ++r)
          pk.h[r] = f2bf(acc[i][j][r] + bias[m0 + 16 * i + rbase + r]);
        *reinterpret_cast<unsigned long long*>(T + (size_t)n * 64 + m) = pk.u;
      }
    }
  } else {
    unsigned short* vb = V + (size_t)b * NC * NN;
#pragma unroll
    for (int i = 0; i < 4; ++i) {
#pragma unroll
      for (int r = 0; r < 4; ++r) {
        int m = m0 + 16 * i + rbase + r;
        float bs = bias[m];
        int c = m - 128;
#pragma unroll
        for (int j = 0; j < 4; ++j) {
          int n = nw + 16 * j + lcol;
          vb[(size_t)c * NN + n] = f2bf(acc[i][j][r] + bs);
        }
      }
    }
  }
}

// ---------------- attention stats: exact m_j, l_j per column ----------------
// grid 256 = (b, 64-j block) with XCD-pair swizzle. 8 waves stripe i independently.
// NO per-iteration barriers; single merge at the end.
__global__ __launch_bounds__(512) void attn_stats(
    const unsigned short* __restrict__ QT, const unsigned short* __restrict__ KT,
    float* __restrict__ Mst, float* __restrict__ Lst) {
  int bid = blockIdx.x;
  int b = (bid & 7) >> 1;
  int jb = ((bid >> 3) << 1) | (bid & 1);
  int j0 = jb * 64;
  int wave = threadIdx.x >> 6, lane = threadIdx.x & 63;
  int lcol = lane & 15, lkg = lane >> 4;

  __shared__ float sm[64][9], sl[64][9];

  const unsigned short* qt = QT + (size_t)b * NN * 64;
  const unsigned short* kt = KT + (size_t)b * NN * 64;

  bf16x8 kfr[4][2];
#pragma unroll
  for (int fn = 0; fn < 4; ++fn)
#pragma unroll
    for (int ks = 0; ks < 2; ++ks)
      kfr[fn][ks] = *reinterpret_cast<const bf16x8*>(
          kt + (size_t)(j0 + 16 * fn + lcol) * 64 + ks * 32 + lkg * 8);

  float m_l[4], l_l[4];
#pragma unroll
  for (int fn = 0; fn < 4; ++fn) { m_l[fn] = -1e30f; l_l[fn] = 0.f; }

  for (int it = 0; it < NN / 128; ++it) {
    int ib = (it * 8 + wave) * 16;   // same strip assignment as attn_pv -> identical S values
    bf16x8 qfr[2];
#pragma unroll
    for (int ks = 0; ks < 2; ++ks)
      qfr[ks] = *reinterpret_cast<const bf16x8*>(
          qt + (size_t)(ib + lcol) * 64 + ks * 32 + lkg * 8);
    f32x4 s[4] = {};
#pragma unroll
    for (int ks = 0; ks < 2; ++ks)
#pragma unroll
      for (int fn = 0; fn < 4; ++fn)
        s[fn] = mfma16(qfr[ks], kfr[fn][ks], s[fn]);
#pragma unroll
    for (int fn = 0; fn < 4; ++fn) {
      float mx = fmaxf(fmaxf(s[fn][0], s[fn][1]), fmaxf(s[fn][2], s[fn][3]));
      float nm = fmaxf(m_l[fn], mx);
      float ps = 0.f;
#pragma unroll
      for (int r = 0; r < 4; ++r) ps += exp2f((s[fn][r] - nm) * LOG2E);
      l_l[fn] = l_l[fn] * exp2f((m_l[fn] - nm) * LOG2E) + ps;
      m_l[fn] = nm;
    }
  }

  // merge the 4 lkg replicas (lanes differing in bits 4,5)
#pragma unroll
  for (int fn = 0; fn < 4; ++fn) {
#pragma unroll
    for (int off = 16; off <= 32; off <<= 1) {
      float om = __shfl_xor(m_l[fn], off), ol = __shfl_xor(l_l[fn], off);
      float nm = fmaxf(m_l[fn], om);
      l_l[fn] = l_l[fn] * exp2f((m_l[fn] - nm) * LOG2E) + ol * exp2f((om - nm) * LOG2E);
      m_l[fn] = nm;
    }
    if (lkg == 0) { sm[16 * fn + lcol][wave] = m_l[fn]; sl[16 * fn + lcol][wave] = l_l[fn]; }
  }
  __syncthreads();
  if (wave == 0) {
    int j = lane;  // 0..63
    float m = -1e30f, l = 0.f;
#pragma unroll
    for (int w = 0; w < 8; ++w) {
      float om = sm[j][w], ol = sl[j][w];
      float nm = fmaxf(m, om);
      l = l * exp2f((m - nm) * LOG2E) + ol * exp2f((om - nm) * LOG2E);
      m = nm;
    }
    Mst[(size_t)b * NN + j0 + j] = m;
    Lst[(size_t)b * NN + j0 + j] = l;
  }
}

// ---------------- attention PV: pure GEMM pipeline with known (m,l) ----------------
// grid 256 = (b, jb) XCD-swizzled, 8 waves. Wave w owns rows c in [64w, 64w+64).
// One raw barrier per iter (lgkmcnt only — V loads stay in flight across it).
__global__ __launch_bounds__(512) void attn_pv(
    const unsigned short* __restrict__ QT, const unsigned short* __restrict__ KT,
    const unsigned short* __restrict__ V, const float* __restrict__ x,
    const float* __restrict__ gamma, const float* __restrict__ Mst,
    const float* __restrict__ Lst, float* __restrict__ out) {
  int bid = blockIdx.x;
  int b = (bid & 7) >> 1;
  int jb = ((bid >> 3) << 1) | (bid & 1);
  int j0 = jb * 64;
  int wave = threadIdx.x >> 6, lane = threadIdx.x & 63;
  int lcol = lane & 15, lkg = lane >> 4;

  __shared__ __align__(16) unsigned short plds[2][64 * 128];  // P^T [j][i] double-buffered

  const unsigned short* qt = QT + (size_t)b * NN * 64;
  const unsigned short* kt = KT + (size_t)b * NN * 64;
  const unsigned short* vp = V + (size_t)b * NC * NN;

  bf16x8 kfr[4][2];
  float mlog[4], lj[4];
#pragma unroll
  for (int fn = 0; fn < 4; ++fn) {
#pragma unroll
    for (int ks = 0; ks < 2; ++ks)
      kfr[fn][ks] = *reinterpret_cast<const bf16x8*>(
          kt + (size_t)(j0 + 16 * fn + lcol) * 64 + ks * 32 + lkg * 8);
    mlog[fn] = Mst[(size_t)b * NN + j0 + 16 * fn + lcol] * LOG2E;
    lj[fn] = Lst[(size_t)b * NN + j0 + 16 * fn + lcol];
  }

  f32x4 oacc[4][4] = {};  // [cm][fn]

  for (int it = 0; it < NN / 128; ++it) {
    int i0 = it * 128;
    char* pbuf = reinterpret_cast<char*>(plds[it & 1]);

    // V fragments for this i-block: issued now, consumed after the barrier (stay in flight)
    bf16x8 vfr[4][4];  // [ks][cm]
#pragma unroll
    for (int ks = 0; ks < 4; ++ks)
#pragma unroll
      for (int cm = 0; cm < 4; ++cm)
        vfr[ks][cm] = *reinterpret_cast<const bf16x8*>(
            vp + (size_t)(64 * wave + 16 * cm + lcol) * NN + i0 + ks * 32 + lkg * 8);

    // ---- S strip: rows [i0+16*wave, +16) x 64 cols ----
    bf16x8 qfr[2];
#pragma unroll
    for (int ks = 0; ks < 2; ++ks)
      qfr[ks] = *reinterpret_cast<const bf16x8*>(
          qt + (size_t)(i0 + 16 * wave + lcol) * 64 + ks * 32 + lkg * 8);
    f32x4 s[4] = {};
#pragma unroll
    for (int ks = 0; ks < 2; ++ks)
#pragma unroll
      for (int fn = 0; fn < 4; ++fn)
        s[fn] = mfma16(qfr[ks], kfr[fn][ks], s[fn]);

    // ---- P = exp2(S*log2e - m*log2e), pack bf16, write P^T swizzled ----
#pragma unroll
    for (int fn = 0; fn < 4; ++fn) {
      union { unsigned short h[4]; unsigned long long u; } pk;
#pragma unroll
      for (int r = 0; r < 4; ++r)
        pk.h[r] = f2bf(exp2f(s[fn][r] * LOG2E - mlog[fn]));
      int j = 16 * fn + lcol;
      int byteoff = (j * 256 + wave * 32 + lkg * 8) ^ ((j & 7) << 4);
      *reinterpret_cast<unsigned long long*>(pbuf + byteoff) = pk.u;
    }

    // ---- raw barrier: drain LDS writes only; V global loads remain in flight ----
    asm volatile("s_waitcnt lgkmcnt(0)" ::: "memory");
    __builtin_amdgcn_s_barrier();
    asm volatile("" ::: "memory");

    // ---- PV: O[64c][64j] += V[c][i-block] * P^T ----
    __builtin_amdgcn_s_setprio(1);
#pragma unroll
    for (int ks = 0; ks < 4; ++ks) {
      bf16x8 pfr[4];
#pragma unroll
      for (int fn = 0; fn < 4; ++fn) {
        int j = 16 * fn + lcol;
        int byteoff = (j * 256 + ks * 64 + lkg * 16) ^ ((j & 7) << 4);
        pfr[fn] = *reinterpret_cast<const bf16x8*>(pbuf + byteoff);
      }
#pragma unroll
      for (int cm = 0; cm < 4; ++cm)
#pragma unroll
        for (int fn = 0; fn < 4; ++fn)
          oacc[cm][fn] = mfma16(vfr[ks][cm], pfr[fn], oacc[cm][fn]);
    }
    __builtin_amdgcn_s_setprio(0);
  }

  // ---- epilogue: out = gamma * O/l + x ----
  float g = gamma[0];
  const float* xb = x + (size_t)b * NC * NN;
  float* ob = out + (size_t)b * NC * NN;
#pragma unroll
  for (int fn = 0; fn < 4; ++fn) {
    float sc = g / lj[fn];
    int j = j0 + 16 * fn + lcol;
#pragma unroll
    for (int cm = 0; cm < 4; ++cm) {
      int c = 64 * wave + 16 * cm + lkg * 4;
#pragma unroll
      for (int r = 0; r < 4; ++r) {
        size_t idx = (size_t)(c + r) * NN + j;
        ob[idx] = oacc[cm][fn][r] * sc + xb[idx];
      }
    }
  }
}

extern "C" void kernel_launch(void* const* d_in, const int* in_sizes, int n_in,
                              void* d_out, int out_size, void* d_ws, size_t ws_size,
                              hipStream_t stream) {
  const float* x  = (const float*)d_in[0];
  const float* wq = (const float*)d_in[1];
  const float* bq = (const float*)d_in[2];
  const float* wk = (const float*)d_in[3];
  const float* bk = (const float*)d_in[4];
  const float* wv = (const float*)d_in[5];
  const float* bv = (const float*)d_in[6];
  const float* gm = (const float*)d_in[7];
  float* out = (float*)d_out;

  char* ws = (char*)d_ws;
  unsigned short* XT = (unsigned short*)(ws);                             // 16 MB
  unsigned short* Vb = (unsigned short*)(ws + (size_t)16 * 1024 * 1024);  // 16 MB
  unsigned short* QT = (unsigned short*)(ws + (size_t)32 * 1024 * 1024);  // 2 MB
  unsigned short* KT = (unsigned short*)(ws + (size_t)34 * 1024 * 1024);  // 2 MB
  unsigned short* Wp = (unsigned short*)(ws + (size_t)36 * 1024 * 1024);  // 640 KB
  float* biasp = (float*)(ws + (size_t)36 * 1024 * 1024 + 704 * 1024);    // 2.5 KB
  float* Mst   = (float*)(ws + (size_t)36 * 1024 * 1024 + 768 * 1024);    // 64 KB
  float* Lst   = (float*)(ws + (size_t)36 * 1024 * 1024 + 832 * 1024);    // 64 KB

  pack_w<<<(NM * NC + 255) / 256, 256, 0, stream>>>(wq, bq, wk, bk, wv, bv, Wp, biasp);
  xpose<<<dim3(NN / 64, NC / 64, NB), 256, 0, stream>>>(x, XT);
  gemm_qkv<<<dim3(NN / 512, NM / 64, NB), 512, 0, stream>>>(Wp, biasp, XT, QT, KT, Vb);
  attn_stats<<<256, 512, 0, stream>>>(QT, KT, Mst, Lst);
  attn_pv<<<256, 512, 0, stream>>>(QT, KT, Vb, x, gm, Mst, Lst, out);
}